// Round 17
// baseline (7792.349 us; speedup 1.0000x reference)
//
#include <hip/hip_runtime.h>

#define NB 16384
#define ND 768
#define NF 8192
#define CMAX 512        // ksel compact list cap per row
#define SEGW 12         // glist slots per (row,tile) segment
#define GSEG 768        // glist u32 per row (64 tiles x 12 slots) == 3072 B == rec row
#define AMAX 128        // ambiguous cap per row (expect ~13)
#define MARG 0.07f      // classification margin (>= 2x bf16-GEMM act error bound)
#define THETA0 2.0f     // GEMM-side candidate threshold (bf16-exact)
#define THETA0_BITS 0x4000u

typedef __attribute__((ext_vector_type(8))) short bf16x8;
typedef __attribute__((ext_vector_type(4))) float f32x4;
typedef __attribute__((ext_vector_type(4))) unsigned int u32x4;
typedef __attribute__((ext_vector_type(2))) float f32x2;

__device__ inline unsigned short f2bf(float f) {
  unsigned u = __float_as_uint(f);
  unsigned r = (u + 0x7FFFu + ((u >> 16) & 1u)) >> 16;
  return (unsigned short)r;
}
__device__ inline float bfbits2f(unsigned u16) { return __uint_as_float(u16 << 16); }

// ---------------------------------------------------------------------------
__global__ __launch_bounds__(256) void cvt_bf16_k(const float* __restrict__ in,
                                                  unsigned short* __restrict__ out) {
  size_t t = (size_t)blockIdx.x * 256 + threadIdx.x;
  const float4* i4 = (const float4*)in;
  float4 a = i4[t * 2], b = i4[t * 2 + 1];
  ushort4 lo = make_ushort4(f2bf(a.x), f2bf(a.y), f2bf(a.z), f2bf(a.w));
  ushort4 hi = make_ushort4(f2bf(b.x), f2bf(b.y), f2bf(b.z), f2bf(b.w));
  ((ushort4*)out)[t * 2] = lo;
  ((ushort4*)out)[t * 2 + 1] = hi;
}

// ---------------------------------------------------------------------------
// fused: Wbf = bf16(W_enc) AND beta[f] = b_enc[f] - dot(dec_bias, W_enc[f])
__global__ __launch_bounds__(256) void cvtW_beta_k(const float* __restrict__ W_enc,
                                                   const float* __restrict__ b_enc,
                                                   const float* __restrict__ dec_bias,
                                                   unsigned short* __restrict__ Wbf,
                                                   float* __restrict__ beta) {
  __shared__ float db[ND];
  const int tid = threadIdx.x, wave = tid >> 6, lane = tid & 63;
  db[tid] = dec_bias[tid];
  db[tid + 256] = dec_bias[tid + 256];
  db[tid + 512] = dec_bias[tid + 512];
  __syncthreads();
  const int f = blockIdx.x * 4 + wave;
  const float* wr = W_enc + (size_t)f * ND + lane * 12;
  float4 v0 = *(const float4*)(wr);
  float4 v1 = *(const float4*)(wr + 4);
  float4 v2 = *(const float4*)(wr + 8);
  const float* d = &db[lane * 12];
  float s = 0.f;
  s = fmaf(v0.x, d[0], s);  s = fmaf(v0.y, d[1], s);
  s = fmaf(v0.z, d[2], s);  s = fmaf(v0.w, d[3], s);
  s = fmaf(v1.x, d[4], s);  s = fmaf(v1.y, d[5], s);
  s = fmaf(v1.z, d[6], s);  s = fmaf(v1.w, d[7], s);
  s = fmaf(v2.x, d[8], s);  s = fmaf(v2.y, d[9], s);
  s = fmaf(v2.z, d[10], s); s = fmaf(v2.w, d[11], s);
  unsigned short* ow = Wbf + (size_t)f * ND + lane * 12;
  *(ushort4*)(ow)     = make_ushort4(f2bf(v0.x), f2bf(v0.y), f2bf(v0.z), f2bf(v0.w));
  *(ushort4*)(ow + 4) = make_ushort4(f2bf(v1.x), f2bf(v1.y), f2bf(v1.z), f2bf(v1.w));
  *(ushort4*)(ow + 8) = make_ushort4(f2bf(v2.x), f2bf(v2.y), f2bf(v2.z), f2bf(v2.w));
#pragma unroll
  for (int off = 32; off; off >>= 1) s += __shfl_down(s, off);
  if (lane == 0) beta[f] = b_enc[f] - s;
}

// ---------------------------------------------------------------------------
__global__ __launch_bounds__(256) void transpose_bf_k(const float* __restrict__ in,
                                                      unsigned short* __restrict__ out) {
  __shared__ float tile[32][33];
  int lx = threadIdx.x & 31;
  int ty = threadIdx.x >> 5;
  int x = blockIdx.x * 32 + lx;  // f
  for (int j = ty; j < 32; j += 8) {
    int y = blockIdx.y * 32 + j;  // d
    tile[j][lx] = in[(size_t)y * NF + x];
  }
  __syncthreads();
  int xo = blockIdx.y * 32 + lx;  // d
  for (int j = ty; j < 32; j += 8) {
    int yo = blockIdx.x * 32 + j;  // f
    out[(size_t)yo * ND + xo] = f2bf(tile[lx][j]);
  }
}

// ---------------------------------------------------------------------------
// bf16 MFMA GEMM v8.2: round-16 proven structure; glist segments now 12-wide
// and written into the out_rec region (row-for-row overlay with rec).
__global__ __launch_bounds__(256, 5) void enc_gemm_bf16(
    const unsigned short* __restrict__ Xb, const unsigned short* __restrict__ Wb,
    const float* __restrict__ beta, unsigned* __restrict__ glist) {
  __shared__ __align__(1024) unsigned short As[128 * 64];  // 16 KB
  __shared__ __align__(1024) unsigned short Bs[128 * 64];  // 16 KB
  const int tid = threadIdx.x;
  const int wave = tid >> 6, lane = tid & 63;
  const int wm = wave >> 1, wn = wave & 1;

  const int orig = blockIdx.y * gridDim.x + blockIdx.x;  // 0..8191
  const int xcd = orig & 7;
  const int local = orig >> 3;
  const int tcol = local >> 4;          // 0..63
  const int trow = (xcd << 4) + (local & 15);
  const int brow = trow << 7;
  const int bcol = tcol << 7;

  f32x4 acc[4][4] = {};

  const int srow = tid >> 3;                                   // 0..31
  const int scol = (((tid & 7) ^ ((tid >> 3) & 7)) << 3);      // pre-swizzled source chunk
  const unsigned short* gA = Xb + (size_t)(brow + srow) * ND + scol;
  const unsigned short* gB = Wb + (size_t)(bcol + srow) * ND + scol;

  // hoisted LDS frag offsets (loop-invariant across all 12 steps)
  int aoff[2][4], boff[2][4];
#pragma unroll
  for (int kk2 = 0; kk2 < 2; ++kk2) {
    const int chunk = ((kk2 << 5) + ((lane >> 4) << 3)) >> 3;
    const int sw = chunk ^ (lane & 7);
#pragma unroll
    for (int m = 0; m < 4; ++m)
      aoff[kk2][m] = ((wm << 6) + (lane & 15) + (m << 4)) * 64 + (sw << 3);
#pragma unroll
    for (int n = 0; n < 4; ++n)
      boff[kk2][n] = ((wn << 6) + (lane & 15) + (n << 4)) * 64 + (sw << 3);
  }

#pragma unroll 1
  for (int step = 0; step < 12; ++step) {
    const int kt = step * 64;
#pragma unroll
    for (int i = 0; i < 4; ++i) {
      __builtin_amdgcn_global_load_lds(
          (const __attribute__((address_space(1))) void*)(gA + (size_t)(i * 32) * ND + kt),
          (__attribute__((address_space(3))) void*)(As + (i * 32 + wave * 8) * 64), 16, 0, 0);
      __builtin_amdgcn_global_load_lds(
          (const __attribute__((address_space(1))) void*)(gB + (size_t)(i * 32) * ND + kt),
          (__attribute__((address_space(3))) void*)(Bs + (i * 32 + wave * 8) * 64), 16, 0, 0);
    }
    __syncthreads();
#pragma unroll
    for (int kk2 = 0; kk2 < 2; ++kk2) {
      bf16x8 a[4], bvv[4];
#pragma unroll
      for (int m = 0; m < 4; ++m) a[m] = *(const bf16x8*)&As[aoff[kk2][m]];
#pragma unroll
      for (int n = 0; n < 4; ++n) bvv[n] = *(const bf16x8*)&Bs[boff[kk2][n]];
#pragma unroll
      for (int m = 0; m < 4; ++m)
#pragma unroll
        for (int n = 0; n < 4; ++n)
          acc[m][n] = __builtin_amdgcn_mfma_f32_16x16x32_bf16(a[m], bvv[n], acc[m][n], 0, 0, 0);
    }
    __syncthreads();
  }

  // ---- epilogue: candidate segments overlaid on the (now dead) As buffer
  unsigned (*wseg)[SEGW] = (unsigned (*)[SEGW])As;        // 128 x 12 u32 = 6 KB
  unsigned* wcnt = (unsigned*)(As + 4096);                // 512 B at byte 8 KB
#pragma unroll
  for (int i = 0; i < 6; ++i) ((unsigned*)wseg)[tid + 256 * i] = 0u;
  if (tid < 128) wcnt[tid] = 0u;
  __syncthreads();

#pragma unroll
  for (int n = 0; n < 4; ++n) {
    float bet = beta[bcol + (wn << 6) + (n << 4) + (lane & 15)];
#pragma unroll
    for (int m = 0; m < 4; ++m) {
#pragma unroll
      for (int r = 0; r < 4; ++r) {
        int row_l = (wm << 6) + (m << 4) + ((lane >> 4) << 2) + r;
        int col_l = (wn << 6) + (n << 4) + (lane & 15);
        float v = fmaxf(acc[m][n][r] + bet, 0.f);
        unsigned short ub = f2bf(v);
        if (ub >= (unsigned short)THETA0_BITS) {
          unsigned p = atomicAdd(&wcnt[row_l], 1u);
          if (p < SEGW) wseg[row_l][p] = ((unsigned)ub << 16) | (unsigned)(bcol + col_l);
        }
      }
    }
  }
  __syncthreads();
  {
    int row = tid >> 1;
    unsigned* dst = &glist[(size_t)(brow + row) * GSEG + tcol * 12];
    if (tid & 1) {
      u32x4 v2 = *(const u32x4*)&wseg[row][8];
      __builtin_nontemporal_store(v2, (u32x4*)&dst[8]);
    } else {
      u32x4 v0 = *(const u32x4*)&wseg[row][0];
      u32x4 v1 = *(const u32x4*)&wseg[row][4];
      if (wcnt[row] > SEGW) v0[0] = 0xFFFFFFFFu;  // overflow sentinel
      __builtin_nontemporal_store(v0, (u32x4*)&dst[0]);
      __builtin_nontemporal_store(v1, (u32x4*)&dst[4]);
    }
  }
}

// ---------------------------------------------------------------------------
// ksel v8: wave-per-row fast path on GEMM-built segments (3 KB/row, read from
// the out_rec overlay). Invalid -> block-cooperative exact fp32 recompute.
// Fused outputs: rec row (overwrites own glist row, safe) + sparse row via
// LDS presence bitmap (d2 kernel eliminated).
__global__ __launch_bounds__(256, 6) void ksel_k(
    const unsigned* __restrict__ glist,
    const float* __restrict__ x, const float* __restrict__ W_enc,
    const float* __restrict__ beta, const unsigned short* __restrict__ WdecBf,
    const float* __restrict__ dec_bias, const int* __restrict__ kptr,
    float* __restrict__ out_rec, float* __restrict__ out_sc) {
  const int tid = threadIdx.x, wave = tid >> 6, lane = tid & 63;
  const int b = blockIdx.x * 4 + wave;
  int k = *kptr; k = k < 1 ? 1 : (k > 64 ? 64 : k);
  const unsigned kk = (unsigned)k;

  __shared__ unsigned clist_s[4][CMAX];
  __shared__ unsigned long long aval_s[4][AMAX];
  __shared__ float selv_s[4][64];
  __shared__ int seli_s[4][64];
  __shared__ int ctrC_s[4], ctrW_s[4], ctrA_s[4];
  __shared__ int blkFb;
  __shared__ float fb_x[ND];
  __shared__ unsigned long long fbl[512];
  __shared__ unsigned fb_thrmax[256];
  __shared__ unsigned long long fb_red[4];
  __shared__ unsigned fb_cnt4[4];
  __shared__ unsigned fbcnt;
  __shared__ unsigned bm[256];

  unsigned* clist = clist_s[wave];
  unsigned long long* aval = aval_s[wave];
  float* selv = selv_s[wave];
  int* seli = seli_s[wave];

  if (tid == 0) blkFb = 0;
  if (lane == 0) { ctrC_s[wave] = 0; ctrW_s[wave] = 0; ctrA_s[wave] = 0; }

  // ---- fast path: load + compact the segmented list (3 KB/row)
  bool bad = false;
  {
    const u32x4* seg4 = (const u32x4*)(glist + (size_t)b * GSEG);
#pragma unroll
    for (int ii = 0; ii < 3; ++ii) {
      u32x4 e4 = __builtin_nontemporal_load(&seg4[lane + (ii << 6)]);
#pragma unroll
      for (int q = 0; q < 4; ++q) {
        unsigned e = e4[q];
        if (e) {
          if ((e & 0xFFFFu) >= (unsigned)NF) bad = true;  // sentinel
          else {
            int p = atomicAdd(&ctrC_s[wave], 1);
            if (p < CMAX) clist[p] = e;
          }
        }
      }
    }
  }
  bad = (__ballot(bad) != 0ull);
  int nraw = ctrC_s[wave];
  int n = nraw < CMAX ? nraw : CMAX;

  // tau via 15-probe bitwise binary search over the list
  unsigned ks[8];
#pragma unroll
  for (int ii = 0; ii < 8; ++ii) {
    int j = lane + (ii << 6);
    ks[ii] = (j < n) ? (clist[j] >> 16) : 0u;
  }
  unsigned T = 0;
  for (int bit = 14; bit >= 0; --bit) {
    unsigned probe = T | (1u << bit);
    int c = 0;
#pragma unroll
    for (int ii = 0; ii < 8; ++ii) c += (ks[ii] >= probe);
#pragma unroll
    for (int off = 32; off; off >>= 1) c += __shfl_xor(c, off);
    if (c >= (int)kk) T = probe;
  }
  float tauf = bfbits2f(T);

  bool valid = !bad && (nraw <= CMAX) && (n >= k) && (tauf >= THETA0 + MARG);
  if (lane == 0 && !valid) atomicOr(&blkFb, 1);
  __syncthreads();

  if (!blkFb) {
    const float thrW = tauf + MARG;
    const float thrA = tauf - MARG;
    for (int j = lane; j < n; j += 64) {
      unsigned e = clist[j];
      float v = bfbits2f(e >> 16);
      int idx = (int)(e & 0xFFFFu);
      if (v > thrW) {
        int p = atomicAdd(&ctrW_s[wave], 1);
        if (p < 63) { selv[p] = v; seli[p] = idx; }
      } else if (v >= thrA) {
        int p = atomicAdd(&ctrA_s[wave], 1);
        if (p < AMAX) aval[p] = (unsigned long long)(unsigned)idx;
      }
    }
    __syncthreads();
    int c = ctrW_s[wave]; if (c > 63) c = 63; if (c > k - 1) c = k - 1;
    int na = ctrA_s[wave]; if (na > AMAX) na = AMAX;

    float xr[12];
#pragma unroll
    for (int cc = 0; cc < 12; ++cc)
      xr[cc] = __builtin_nontemporal_load(&x[(size_t)b * ND + lane + 64 * cc]);
    for (int j = 0; j < na; j += 2) {
      int f0 = (int)(unsigned)aval[j];
      int f1 = (j + 1 < na) ? (int)(unsigned)aval[j + 1] : f0;
      const float* w0 = W_enc + (size_t)f0 * ND;
      const float* w1 = W_enc + (size_t)f1 * ND;
      float s0 = 0.f, s1 = 0.f;
#pragma unroll
      for (int cc = 0; cc < 12; ++cc) {
        s0 = fmaf(xr[cc], w0[lane + 64 * cc], s0);
        s1 = fmaf(xr[cc], w1[lane + 64 * cc], s1);
      }
#pragma unroll
      for (int off = 32; off; off >>= 1) {
        s0 += __shfl_xor(s0, off);
        s1 += __shfl_xor(s1, off);
      }
      if (lane == 0) {
        float v0 = fmaxf(s0 + beta[f0], 0.f);
        aval[j] = (((unsigned long long)__float_as_uint(v0)) << 13) | (unsigned)(8191 - f0);
        if (j + 1 < na) {
          float v1 = fmaxf(s1 + beta[f1], 0.f);
          aval[j + 1] = (((unsigned long long)__float_as_uint(v1)) << 13) | (unsigned)(8191 - f1);
        }
      }
    }
    __syncthreads();

    unsigned long long p0 = (lane < na) ? aval[lane] : 0ull;
    unsigned long long p1 = (lane + 64 < na) ? aval[lane + 64] : 0ull;
    int rounds = k - c; if (rounds < 0) rounds = 0;
    for (int r = 0; r < rounds; ++r) {
      unsigned long long m = p0 > p1 ? p0 : p1;
#pragma unroll
      for (int off = 32; off; off >>= 1) {
        unsigned long long o = __shfl_xor(m, off);
        if (o > m) m = o;
      }
      if (lane == 0) {
        if (m) { selv[c + r] = __uint_as_float((unsigned)(m >> 13)); seli[c + r] = 8191 - (int)(m & 0x1FFFull); }
        else   { selv[c + r] = 0.f; seli[c + r] = 0; }
      }
      if (p0 == m) p0 = 0;
      if (p1 == m) p1 = 0;
    }
    __syncthreads();
  } else {
    // ---- fallback: block-cooperative exact fp32 recompute, rows sequential
    for (int r = 0; r < 4; ++r) {
      const int row = blockIdx.x * 4 + r;
      fb_x[tid] = x[(size_t)row * ND + tid];
      fb_x[tid + 256] = x[(size_t)row * ND + tid + 256];
      fb_x[tid + 512] = x[(size_t)row * ND + tid + 512];
      __syncthreads();
      unsigned mymax = 0u;
      for (int j = 0; j < 32; ++j) {
        int f = tid * 32 + j;
        const float* w = W_enc + (size_t)f * ND;
        float s = 0.f;
#pragma unroll 8
        for (int d = 0; d < ND; ++d) s = fmaf(fb_x[d], w[d], s);
        unsigned bits = __float_as_uint(fmaxf(s + beta[f], 0.f));
        if (bits > mymax) mymax = bits;
      }
      fb_thrmax[tid] = mymax;
      __syncthreads();
      unsigned L = 0;
      for (int bit = 30; bit >= 0; --bit) {
        unsigned probe = L | (1u << bit);
        unsigned long long bl = __ballot(fb_thrmax[tid] >= probe);
        if (lane == 0) fb_cnt4[wave] = (unsigned)__popcll(bl);
        __syncthreads();
        unsigned tot = fb_cnt4[0] + fb_cnt4[1] + fb_cnt4[2] + fb_cnt4[3];
        if (tot >= kk) L = probe;
        __syncthreads();
      }
      if (tid == 0) fbcnt = 0u;
      __syncthreads();
      for (int j = 0; j < 32; ++j) {
        int f = tid * 32 + j;
        const float* w = W_enc + (size_t)f * ND;
        float s = 0.f;
#pragma unroll 8
        for (int d = 0; d < ND; ++d) s = fmaf(fb_x[d], w[d], s);
        unsigned bits = __float_as_uint(fmaxf(s + beta[f], 0.f));
        if (bits >= L) {
          unsigned p = atomicAdd(&fbcnt, 1u);
          if (p < 512) fbl[p] = (((unsigned long long)bits) << 13) | (unsigned)(8191 - f);
        }
      }
      __syncthreads();
      int n2 = (int)(fbcnt < 512u ? fbcnt : 512u);
      for (int rr = 0; rr < k; ++rr) {
        unsigned long long best = 0ull;
        for (int j2 = tid; j2 < n2; j2 += 256)
          if (fbl[j2] > best) best = fbl[j2];
#pragma unroll
        for (int off = 32; off; off >>= 1) {
          unsigned long long o = __shfl_xor(best, off);
          if (o > best) best = o;
        }
        if (lane == 0) fb_red[wave] = best;
        __syncthreads();
        unsigned long long m = fb_red[0];
#pragma unroll
        for (int w2 = 1; w2 < 4; ++w2)
          if (fb_red[w2] > m) m = fb_red[w2];
        if (tid == 0) {
          if (m) { selv_s[r][rr] = __uint_as_float((unsigned)(m >> 13)); seli_s[r][rr] = 8191 - (int)(m & 0x1FFFull); }
          else   { selv_s[r][rr] = 0.f; seli_s[r][rr] = 0; }
        }
        for (int j2 = tid; j2 < n2; j2 += 256)
          if (fbl[j2] == m) fbl[j2] = 0ull;
        __syncthreads();
      }
      __syncthreads();
    }
  }

  // ---- fused reconstruction (per-wave; overwrites own glist row -- safe,
  // segment already consumed into LDS by this wave)
  float acc[12];
#pragma unroll
  for (int cc = 0; cc < 6; ++cc) {
    float2 db = *(const float2*)&dec_bias[cc * 128 + lane * 2];
    acc[2 * cc] = db.x; acc[2 * cc + 1] = db.y;
  }
#define RECON_TERM(r)                                                          \
  {                                                                            \
    int f = seli[r]; float v = selv[r];                                        \
    const unsigned short* wd = WdecBf + (size_t)f * ND;                        \
    _Pragma("unroll")                                                          \
    for (int cc = 0; cc < 6; ++cc) {                                           \
      unsigned pr = *(const unsigned*)&wd[cc * 128 + lane * 2];                \
      acc[2 * cc] = fmaf(v, bfbits2f(pr & 0xFFFFu), acc[2 * cc]);              \
      acc[2 * cc + 1] = fmaf(v, bfbits2f(pr >> 16), acc[2 * cc + 1]);          \
    }                                                                          \
  }
  if (k == 32) {
#pragma unroll
    for (int r = 0; r < 32; ++r) RECON_TERM(r)
  } else {
    for (int r = 0; r < k; ++r) RECON_TERM(r)
  }
#pragma unroll
  for (int cc = 0; cc < 6; ++cc) {
    f32x2 st = {acc[2 * cc], acc[2 * cc + 1]};
    __builtin_nontemporal_store(st, (f32x2*)&out_rec[(size_t)b * ND + cc * 128 + lane * 2]);
  }

  // ---- fused sparse-row writes (replaces d2): 4 rows sequential, LDS bitmap
  __syncthreads();
  for (int r = 0; r < 4; ++r) {
    bm[tid] = 0u;
    __syncthreads();
    if (tid < k) {
      int ix = seli_s[r][tid];
      atomicOr(&bm[ix >> 5], 1u << (ix & 31));
    }
    __syncthreads();
    float* rowp = out_sc + (size_t)(blockIdx.x * 4 + r) * NF;
#pragma unroll
    for (int i = 0; i < 8; ++i) {
      int o = (tid + (i << 8)) << 2;  // float offset, multiple of 4
      unsigned nib = (bm[o >> 5] >> (o & 31)) & 0xFu;
      f32x4 val = {0.f, 0.f, 0.f, 0.f};
      if (nib) {
#pragma unroll
        for (int j = 0; j < 4; ++j) {
          if ((nib >> j) & 1) {
            int idx = o + j;
            float bestv = 0.f;
            for (int t2 = 0; t2 < k; ++t2)
              if (seli_s[r][t2] == idx && selv_s[r][t2] > bestv) bestv = selv_s[r][t2];
            val[j] = bestv;
          }
        }
      }
      __builtin_nontemporal_store(val, (f32x4*)&rowp[o]);
    }
    __syncthreads();
  }
}

// ---------------------------------------------------------------------------
extern "C" void kernel_launch(void* const* d_in, const int* in_sizes, int n_in,
                              void* d_out, int out_size, void* d_ws, size_t ws_size,
                              hipStream_t stream) {
  const float* x        = (const float*)d_in[0];
  const float* W_enc    = (const float*)d_in[1];
  const float* b_enc    = (const float*)d_in[2];
  const float* W_dec    = (const float*)d_in[3];
  const float* dec_bias = (const float*)d_in[4];
  const int*   kptr     = (const int*)d_in[5];

  float* out_rec = (float*)d_out;                    // [NB, ND] (glist overlay)
  float* out_sc  = (float*)d_out + (size_t)NB * ND;  // [NB, NF]

  // glist overlays out_rec row-for-row: GSEG*4 B == ND*4 B == 3072 B per row
  unsigned* glist = (unsigned*)out_rec;              // 48 MB, rewritten by GEMM

  // Xbf/Wbf carved from the sparse-code output region (dead after GEMM;
  // overwritten by ksel's fused sparse writes afterwards)
  char* scb = (char*)out_sc;
  unsigned short* Xbf = (unsigned short*)scb;                 // 24 MB
  unsigned short* Wbf = (unsigned short*)(scb + 25165824);    // 12 MB

  char* ws = (char*)d_ws;
  unsigned short* WdecBf = (unsigned short*)ws;        // 12,582,912 B
  float* beta = (float*)(ws + 12582912);               //     32,768 B

  cvt_bf16_k<<<(NB * ND) / 2048, 256, 0, stream>>>(x, Xbf);
  cvtW_beta_k<<<NF / 4, 256, 0, stream>>>(W_enc, b_enc, dec_bias, Wbf, beta);
  transpose_bf_k<<<dim3(NF / 32, ND / 32), 256, 0, stream>>>(W_dec, WdecBf);
  enc_gemm_bf16<<<dim3(NF / 128, NB / 128), 256, 0, stream>>>(Xbf, Wbf, beta, glist);
  ksel_k<<<NB / 4, 256, 0, stream>>>(glist, x, W_enc, beta, WdecBf, dec_bias, kptr,
                                     out_rec, out_sc);
}

// Round 18
// 669.928 us; speedup vs baseline: 11.6316x; 11.6316x over previous
//
#include <hip/hip_runtime.h>

#define NB 16384
#define ND 768
#define NF 8192
#define CMAX 512        // ksel compact list cap per row
#define SEGW 12         // glist slots per (row,tile) segment
#define GSEG 768        // glist u32 per row (64 tiles x 12 slots) == 3072 B == rec row
#define AMAX 128        // ambiguous cap per row (expect ~13)
#define MARG 0.07f      // classification margin (>= 2x bf16-GEMM act error bound)
#define THETA0 2.0f     // GEMM-side candidate threshold (bf16-exact)
#define THETA0_BITS 0x4000u

typedef __attribute__((ext_vector_type(8))) short bf16x8;
typedef __attribute__((ext_vector_type(4))) float f32x4;
typedef __attribute__((ext_vector_type(4))) unsigned int u32x4;
typedef __attribute__((ext_vector_type(2))) float f32x2;

__device__ inline unsigned short f2bf(float f) {
  unsigned u = __float_as_uint(f);
  unsigned r = (u + 0x7FFFu + ((u >> 16) & 1u)) >> 16;
  return (unsigned short)r;
}
__device__ inline float bfbits2f(unsigned u16) { return __uint_as_float(u16 << 16); }

// ---------------------------------------------------------------------------
__global__ __launch_bounds__(256) void cvt_bf16_k(const float* __restrict__ in,
                                                  unsigned short* __restrict__ out) {
  size_t t = (size_t)blockIdx.x * 256 + threadIdx.x;
  const float4* i4 = (const float4*)in;
  float4 a = i4[t * 2], b = i4[t * 2 + 1];
  ushort4 lo = make_ushort4(f2bf(a.x), f2bf(a.y), f2bf(a.z), f2bf(a.w));
  ushort4 hi = make_ushort4(f2bf(b.x), f2bf(b.y), f2bf(b.z), f2bf(b.w));
  ((ushort4*)out)[t * 2] = lo;
  ((ushort4*)out)[t * 2 + 1] = hi;
}

// ---------------------------------------------------------------------------
// fused: Wbf = bf16(W_enc) AND beta[f] = b_enc[f] - dot(dec_bias, W_enc[f])
__global__ __launch_bounds__(256) void cvtW_beta_k(const float* __restrict__ W_enc,
                                                   const float* __restrict__ b_enc,
                                                   const float* __restrict__ dec_bias,
                                                   unsigned short* __restrict__ Wbf,
                                                   float* __restrict__ beta) {
  __shared__ float db[ND];
  const int tid = threadIdx.x, wave = tid >> 6, lane = tid & 63;
  db[tid] = dec_bias[tid];
  db[tid + 256] = dec_bias[tid + 256];
  db[tid + 512] = dec_bias[tid + 512];
  __syncthreads();
  const int f = blockIdx.x * 4 + wave;
  const float* wr = W_enc + (size_t)f * ND + lane * 12;
  float4 v0 = *(const float4*)(wr);
  float4 v1 = *(const float4*)(wr + 4);
  float4 v2 = *(const float4*)(wr + 8);
  const float* d = &db[lane * 12];
  float s = 0.f;
  s = fmaf(v0.x, d[0], s);  s = fmaf(v0.y, d[1], s);
  s = fmaf(v0.z, d[2], s);  s = fmaf(v0.w, d[3], s);
  s = fmaf(v1.x, d[4], s);  s = fmaf(v1.y, d[5], s);
  s = fmaf(v1.z, d[6], s);  s = fmaf(v1.w, d[7], s);
  s = fmaf(v2.x, d[8], s);  s = fmaf(v2.y, d[9], s);
  s = fmaf(v2.z, d[10], s); s = fmaf(v2.w, d[11], s);
  unsigned short* ow = Wbf + (size_t)f * ND + lane * 12;
  *(ushort4*)(ow)     = make_ushort4(f2bf(v0.x), f2bf(v0.y), f2bf(v0.z), f2bf(v0.w));
  *(ushort4*)(ow + 4) = make_ushort4(f2bf(v1.x), f2bf(v1.y), f2bf(v1.z), f2bf(v1.w));
  *(ushort4*)(ow + 8) = make_ushort4(f2bf(v2.x), f2bf(v2.y), f2bf(v2.z), f2bf(v2.w));
#pragma unroll
  for (int off = 32; off; off >>= 1) s += __shfl_down(s, off);
  if (lane == 0) beta[f] = b_enc[f] - s;
}

// ---------------------------------------------------------------------------
__global__ __launch_bounds__(256) void transpose_bf_k(const float* __restrict__ in,
                                                      unsigned short* __restrict__ out) {
  __shared__ float tile[32][33];
  int lx = threadIdx.x & 31;
  int ty = threadIdx.x >> 5;
  int x = blockIdx.x * 32 + lx;  // f
  for (int j = ty; j < 32; j += 8) {
    int y = blockIdx.y * 32 + j;  // d
    tile[j][lx] = in[(size_t)y * NF + x];
  }
  __syncthreads();
  int xo = blockIdx.y * 32 + lx;  // d
  for (int j = ty; j < 32; j += 8) {
    int yo = blockIdx.x * 32 + j;  // f
    out[(size_t)yo * ND + xo] = f2bf(tile[lx][j]);
  }
}

// ---------------------------------------------------------------------------
// bf16 MFMA GEMM v8.2 (round-16/17 proven): glist segments 12-wide written
// into the out_rec region (row-for-row overlay with rec).
__global__ __launch_bounds__(256, 5) void enc_gemm_bf16(
    const unsigned short* __restrict__ Xb, const unsigned short* __restrict__ Wb,
    const float* __restrict__ beta, unsigned* __restrict__ glist) {
  __shared__ __align__(1024) unsigned short As[128 * 64];  // 16 KB
  __shared__ __align__(1024) unsigned short Bs[128 * 64];  // 16 KB
  const int tid = threadIdx.x;
  const int wave = tid >> 6, lane = tid & 63;
  const int wm = wave >> 1, wn = wave & 1;

  const int orig = blockIdx.y * gridDim.x + blockIdx.x;  // 0..8191
  const int xcd = orig & 7;
  const int local = orig >> 3;
  const int tcol = local >> 4;          // 0..63
  const int trow = (xcd << 4) + (local & 15);
  const int brow = trow << 7;
  const int bcol = tcol << 7;

  f32x4 acc[4][4] = {};

  const int srow = tid >> 3;                                   // 0..31
  const int scol = (((tid & 7) ^ ((tid >> 3) & 7)) << 3);      // pre-swizzled source chunk
  const unsigned short* gA = Xb + (size_t)(brow + srow) * ND + scol;
  const unsigned short* gB = Wb + (size_t)(bcol + srow) * ND + scol;

  int aoff[2][4], boff[2][4];
#pragma unroll
  for (int kk2 = 0; kk2 < 2; ++kk2) {
    const int chunk = ((kk2 << 5) + ((lane >> 4) << 3)) >> 3;
    const int sw = chunk ^ (lane & 7);
#pragma unroll
    for (int m = 0; m < 4; ++m)
      aoff[kk2][m] = ((wm << 6) + (lane & 15) + (m << 4)) * 64 + (sw << 3);
#pragma unroll
    for (int n = 0; n < 4; ++n)
      boff[kk2][n] = ((wn << 6) + (lane & 15) + (n << 4)) * 64 + (sw << 3);
  }

#pragma unroll 1
  for (int step = 0; step < 12; ++step) {
    const int kt = step * 64;
#pragma unroll
    for (int i = 0; i < 4; ++i) {
      __builtin_amdgcn_global_load_lds(
          (const __attribute__((address_space(1))) void*)(gA + (size_t)(i * 32) * ND + kt),
          (__attribute__((address_space(3))) void*)(As + (i * 32 + wave * 8) * 64), 16, 0, 0);
      __builtin_amdgcn_global_load_lds(
          (const __attribute__((address_space(1))) void*)(gB + (size_t)(i * 32) * ND + kt),
          (__attribute__((address_space(3))) void*)(Bs + (i * 32 + wave * 8) * 64), 16, 0, 0);
    }
    __syncthreads();
#pragma unroll
    for (int kk2 = 0; kk2 < 2; ++kk2) {
      bf16x8 a[4], bvv[4];
#pragma unroll
      for (int m = 0; m < 4; ++m) a[m] = *(const bf16x8*)&As[aoff[kk2][m]];
#pragma unroll
      for (int n = 0; n < 4; ++n) bvv[n] = *(const bf16x8*)&Bs[boff[kk2][n]];
#pragma unroll
      for (int m = 0; m < 4; ++m)
#pragma unroll
        for (int n = 0; n < 4; ++n)
          acc[m][n] = __builtin_amdgcn_mfma_f32_16x16x32_bf16(a[m], bvv[n], acc[m][n], 0, 0, 0);
    }
    __syncthreads();
  }

  // ---- epilogue: candidate segments overlaid on the (now dead) As buffer
  unsigned (*wseg)[SEGW] = (unsigned (*)[SEGW])As;        // 128 x 12 u32 = 6 KB
  unsigned* wcnt = (unsigned*)(As + 4096);                // 512 B at byte 8 KB
#pragma unroll
  for (int i = 0; i < 6; ++i) ((unsigned*)wseg)[tid + 256 * i] = 0u;
  if (tid < 128) wcnt[tid] = 0u;
  __syncthreads();

#pragma unroll
  for (int n = 0; n < 4; ++n) {
    float bet = beta[bcol + (wn << 6) + (n << 4) + (lane & 15)];
#pragma unroll
    for (int m = 0; m < 4; ++m) {
#pragma unroll
      for (int r = 0; r < 4; ++r) {
        int row_l = (wm << 6) + (m << 4) + ((lane >> 4) << 2) + r;
        int col_l = (wn << 6) + (n << 4) + (lane & 15);
        float v = fmaxf(acc[m][n][r] + bet, 0.f);
        unsigned short ub = f2bf(v);
        if (ub >= (unsigned short)THETA0_BITS) {
          unsigned p = atomicAdd(&wcnt[row_l], 1u);
          if (p < SEGW) wseg[row_l][p] = ((unsigned)ub << 16) | (unsigned)(bcol + col_l);
        }
      }
    }
  }
  __syncthreads();
  {
    int row = tid >> 1;
    unsigned* dst = &glist[(size_t)(brow + row) * GSEG + tcol * 12];
    if (tid & 1) {
      u32x4 v2 = *(const u32x4*)&wseg[row][8];
      __builtin_nontemporal_store(v2, (u32x4*)&dst[8]);
    } else {
      u32x4 v0 = *(const u32x4*)&wseg[row][0];
      u32x4 v1 = *(const u32x4*)&wseg[row][4];
      if (wcnt[row] > SEGW) v0[0] = 0xFFFFFFFFu;  // overflow sentinel (slot 0)
      __builtin_nontemporal_store(v0, (u32x4*)&dst[0]);
      __builtin_nontemporal_store(v1, (u32x4*)&dst[4]);
    }
  }
}

// ---------------------------------------------------------------------------
// ksel v9: wave-per-row; lane L owns segment L (12 u32). Sentinel segments
// are skipped and their 128-col tile recomputed EXACTLY by the wave (~5 us)
// -- no block fallback for overflow. Block fallback retained only for the
// statistically-impossible n<k / nraw>CMAX / tau-too-low cases.
// Fused outputs: rec row (overwrites own glist row) + sparse row via bitmap.
__global__ __launch_bounds__(256, 6) void ksel_k(
    const unsigned* __restrict__ glist,
    const float* __restrict__ x, const float* __restrict__ W_enc,
    const float* __restrict__ beta, const unsigned short* __restrict__ WdecBf,
    const float* __restrict__ dec_bias, const int* __restrict__ kptr,
    float* __restrict__ out_rec, float* __restrict__ out_sc) {
  const int tid = threadIdx.x, wave = tid >> 6, lane = tid & 63;
  const int b = blockIdx.x * 4 + wave;
  int k = *kptr; k = k < 1 ? 1 : (k > 64 ? 64 : k);
  const unsigned kk = (unsigned)k;

  __shared__ unsigned clist_s[4][CMAX];
  __shared__ unsigned long long aval_s[4][AMAX];
  __shared__ float selv_s[4][64];
  __shared__ int seli_s[4][64];
  __shared__ int ctrC_s[4], ctrW_s[4], ctrA_s[4];
  __shared__ int blkFb;
  __shared__ float fb_x[ND];
  __shared__ unsigned long long fbl[512];
  __shared__ unsigned fb_thrmax[256];
  __shared__ unsigned long long fb_red[4];
  __shared__ unsigned fb_cnt4[4];
  __shared__ unsigned fbcnt;
  __shared__ unsigned bm[256];

  unsigned* clist = clist_s[wave];
  unsigned long long* aval = aval_s[wave];
  float* selv = selv_s[wave];
  int* seli = seli_s[wave];

  if (tid == 0) blkFb = 0;
  if (lane == 0) { ctrC_s[wave] = 0; ctrW_s[wave] = 0; ctrA_s[wave] = 0; }

  // x row fragment (used by ambiguous dots AND sentinel-tile recompute)
  float xr[12];
#pragma unroll
  for (int cc = 0; cc < 12; ++cc)
    xr[cc] = __builtin_nontemporal_load(&x[(size_t)b * ND + lane + 64 * cc]);

  // ---- load segments: lane L owns segment (tile) L
  u32x4 e0, e1, e2;
  {
    const u32x4* seg4 = (const u32x4*)(glist + (size_t)b * GSEG);
    e0 = __builtin_nontemporal_load(&seg4[lane * 3]);
    e1 = __builtin_nontemporal_load(&seg4[lane * 3 + 1]);
    e2 = __builtin_nontemporal_load(&seg4[lane * 3 + 2]);
  }
  const bool sent = (e0[0] == 0xFFFFFFFFu);
  if (!sent) {
#pragma unroll
    for (int q = 0; q < 4; ++q) {
      unsigned a0 = e0[q], a1 = e1[q], a2 = e2[q];
      if (a0) { int p = atomicAdd(&ctrC_s[wave], 1); if (p < CMAX) clist[p] = a0; }
      if (a1) { int p = atomicAdd(&ctrC_s[wave], 1); if (p < CMAX) clist[p] = a1; }
      if (a2) { int p = atomicAdd(&ctrC_s[wave], 1); if (p < CMAX) clist[p] = a2; }
    }
  }

  // ---- sentinel tiles: wave recomputes the 128 acts exactly (fp32), appends
  unsigned long long smask = __ballot(sent);
  while (smask) {
    int t = __ffsll(smask) - 1;
    smask &= smask - 1;
    int fbase = t << 7;
    for (int fi = 0; fi < 128; fi += 2) {
      int f0 = fbase + fi, f1 = fbase + fi + 1;
      const float* w0 = W_enc + (size_t)f0 * ND;
      const float* w1 = W_enc + (size_t)f1 * ND;
      float s0 = 0.f, s1 = 0.f;
#pragma unroll
      for (int cc = 0; cc < 12; ++cc) {
        s0 = fmaf(xr[cc], w0[lane + 64 * cc], s0);
        s1 = fmaf(xr[cc], w1[lane + 64 * cc], s1);
      }
#pragma unroll
      for (int off = 32; off; off >>= 1) {
        s0 += __shfl_xor(s0, off);
        s1 += __shfl_xor(s1, off);
      }
      if (lane == 0) {
        unsigned short u0 = f2bf(fmaxf(s0 + beta[f0], 0.f));
        if (u0 >= (unsigned short)THETA0_BITS) {
          int p = atomicAdd(&ctrC_s[wave], 1);
          if (p < CMAX) clist[p] = ((unsigned)u0 << 16) | (unsigned)f0;
        }
        unsigned short u1 = f2bf(fmaxf(s1 + beta[f1], 0.f));
        if (u1 >= (unsigned short)THETA0_BITS) {
          int p = atomicAdd(&ctrC_s[wave], 1);
          if (p < CMAX) clist[p] = ((unsigned)u1 << 16) | (unsigned)f1;
        }
      }
    }
  }

  int nraw = ctrC_s[wave];
  int n = nraw < CMAX ? nraw : CMAX;

  // tau via 15-probe bitwise binary search over the list
  unsigned ks[8];
#pragma unroll
  for (int ii = 0; ii < 8; ++ii) {
    int j = lane + (ii << 6);
    ks[ii] = (j < n) ? (clist[j] >> 16) : 0u;
  }
  unsigned T = 0;
  for (int bit = 14; bit >= 0; --bit) {
    unsigned probe = T | (1u << bit);
    int c = 0;
#pragma unroll
    for (int ii = 0; ii < 8; ++ii) c += (ks[ii] >= probe);
#pragma unroll
    for (int off = 32; off; off >>= 1) c += __shfl_xor(c, off);
    if (c >= (int)kk) T = probe;
  }
  float tauf = bfbits2f(T);

  bool valid = (nraw <= CMAX) && (n >= k) && (tauf >= THETA0 + MARG + 0.01f);
  if (lane == 0 && !valid) atomicOr(&blkFb, 1);
  __syncthreads();

  if (!blkFb) {
    const float thrW = tauf + MARG;
    const float thrA = tauf - MARG;
    for (int j = lane; j < n; j += 64) {
      unsigned e = clist[j];
      float v = bfbits2f(e >> 16);
      int idx = (int)(e & 0xFFFFu);
      if (v > thrW) {
        int p = atomicAdd(&ctrW_s[wave], 1);
        if (p < 63) { selv[p] = v; seli[p] = idx; }
      } else if (v >= thrA) {
        int p = atomicAdd(&ctrA_s[wave], 1);
        if (p < AMAX) aval[p] = (unsigned long long)(unsigned)idx;
      }
    }
    __syncthreads();
    int c = ctrW_s[wave]; if (c > 63) c = 63; if (c > k - 1) c = k - 1;
    int na = ctrA_s[wave]; if (na > AMAX) na = AMAX;

    for (int j = 0; j < na; j += 2) {
      int f0 = (int)(unsigned)aval[j];
      int f1 = (j + 1 < na) ? (int)(unsigned)aval[j + 1] : f0;
      const float* w0 = W_enc + (size_t)f0 * ND;
      const float* w1 = W_enc + (size_t)f1 * ND;
      float s0 = 0.f, s1 = 0.f;
#pragma unroll
      for (int cc = 0; cc < 12; ++cc) {
        s0 = fmaf(xr[cc], w0[lane + 64 * cc], s0);
        s1 = fmaf(xr[cc], w1[lane + 64 * cc], s1);
      }
#pragma unroll
      for (int off = 32; off; off >>= 1) {
        s0 += __shfl_xor(s0, off);
        s1 += __shfl_xor(s1, off);
      }
      if (lane == 0) {
        float v0 = fmaxf(s0 + beta[f0], 0.f);
        aval[j] = (((unsigned long long)__float_as_uint(v0)) << 13) | (unsigned)(8191 - f0);
        if (j + 1 < na) {
          float v1 = fmaxf(s1 + beta[f1], 0.f);
          aval[j + 1] = (((unsigned long long)__float_as_uint(v1)) << 13) | (unsigned)(8191 - f1);
        }
      }
    }
    __syncthreads();

    unsigned long long p0 = (lane < na) ? aval[lane] : 0ull;
    unsigned long long p1 = (lane + 64 < na) ? aval[lane + 64] : 0ull;
    int rounds = k - c; if (rounds < 0) rounds = 0;
    for (int r = 0; r < rounds; ++r) {
      unsigned long long m = p0 > p1 ? p0 : p1;
#pragma unroll
      for (int off = 32; off; off >>= 1) {
        unsigned long long o = __shfl_xor(m, off);
        if (o > m) m = o;
      }
      if (lane == 0) {
        if (m) { selv[c + r] = __uint_as_float((unsigned)(m >> 13)); seli[c + r] = 8191 - (int)(m & 0x1FFFull); }
        else   { selv[c + r] = 0.f; seli[c + r] = 0; }
      }
      if (p0 == m) p0 = 0;
      if (p1 == m) p1 = 0;
    }
    __syncthreads();
  } else {
    // ---- fallback (statistically unreachable): block-cooperative exact
    for (int r = 0; r < 4; ++r) {
      const int row = blockIdx.x * 4 + r;
      fb_x[tid] = x[(size_t)row * ND + tid];
      fb_x[tid + 256] = x[(size_t)row * ND + tid + 256];
      fb_x[tid + 512] = x[(size_t)row * ND + tid + 512];
      __syncthreads();
      unsigned mymax = 0u;
      for (int j = 0; j < 32; ++j) {
        int f = tid * 32 + j;
        const float* w = W_enc + (size_t)f * ND;
        float s = 0.f;
#pragma unroll 8
        for (int d = 0; d < ND; ++d) s = fmaf(fb_x[d], w[d], s);
        unsigned bits = __float_as_uint(fmaxf(s + beta[f], 0.f));
        if (bits > mymax) mymax = bits;
      }
      fb_thrmax[tid] = mymax;
      __syncthreads();
      unsigned L = 0;
      for (int bit = 30; bit >= 0; --bit) {
        unsigned probe = L | (1u << bit);
        unsigned long long bl = __ballot(fb_thrmax[tid] >= probe);
        if (lane == 0) fb_cnt4[wave] = (unsigned)__popcll(bl);
        __syncthreads();
        unsigned tot = fb_cnt4[0] + fb_cnt4[1] + fb_cnt4[2] + fb_cnt4[3];
        if (tot >= kk) L = probe;
        __syncthreads();
      }
      if (tid == 0) fbcnt = 0u;
      __syncthreads();
      for (int j = 0; j < 32; ++j) {
        int f = tid * 32 + j;
        const float* w = W_enc + (size_t)f * ND;
        float s = 0.f;
#pragma unroll 8
        for (int d = 0; d < ND; ++d) s = fmaf(fb_x[d], w[d], s);
        unsigned bits = __float_as_uint(fmaxf(s + beta[f], 0.f));
        if (bits >= L) {
          unsigned p = atomicAdd(&fbcnt, 1u);
          if (p < 512) fbl[p] = (((unsigned long long)bits) << 13) | (unsigned)(8191 - f);
        }
      }
      __syncthreads();
      int n2 = (int)(fbcnt < 512u ? fbcnt : 512u);
      for (int rr = 0; rr < k; ++rr) {
        unsigned long long best = 0ull;
        for (int j2 = tid; j2 < n2; j2 += 256)
          if (fbl[j2] > best) best = fbl[j2];
#pragma unroll
        for (int off = 32; off; off >>= 1) {
          unsigned long long o = __shfl_xor(best, off);
          if (o > best) best = o;
        }
        if (lane == 0) fb_red[wave] = best;
        __syncthreads();
        unsigned long long m = fb_red[0];
#pragma unroll
        for (int w2 = 1; w2 < 4; ++w2)
          if (fb_red[w2] > m) m = fb_red[w2];
        if (tid == 0) {
          if (m) { selv_s[r][rr] = __uint_as_float((unsigned)(m >> 13)); seli_s[r][rr] = 8191 - (int)(m & 0x1FFFull); }
          else   { selv_s[r][rr] = 0.f; seli_s[r][rr] = 0; }
        }
        for (int j2 = tid; j2 < n2; j2 += 256)
          if (fbl[j2] == m) fbl[j2] = 0ull;
        __syncthreads();
      }
      __syncthreads();
    }
  }

  // ---- fused reconstruction (per-wave; overwrites own glist row -- safe)
  float acc[12];
#pragma unroll
  for (int cc = 0; cc < 6; ++cc) {
    float2 db = *(const float2*)&dec_bias[cc * 128 + lane * 2];
    acc[2 * cc] = db.x; acc[2 * cc + 1] = db.y;
  }
#define RECON_TERM(r)                                                          \
  {                                                                            \
    int f = seli[r]; float v = selv[r];                                        \
    const unsigned short* wd = WdecBf + (size_t)f * ND;                        \
    _Pragma("unroll")                                                          \
    for (int cc = 0; cc < 6; ++cc) {                                           \
      unsigned pr = *(const unsigned*)&wd[cc * 128 + lane * 2];                \
      acc[2 * cc] = fmaf(v, bfbits2f(pr & 0xFFFFu), acc[2 * cc]);              \
      acc[2 * cc + 1] = fmaf(v, bfbits2f(pr >> 16), acc[2 * cc + 1]);          \
    }                                                                          \
  }
  if (k == 32) {
#pragma unroll
    for (int r = 0; r < 32; ++r) RECON_TERM(r)
  } else {
    for (int r = 0; r < k; ++r) RECON_TERM(r)
  }
#pragma unroll
  for (int cc = 0; cc < 6; ++cc) {
    f32x2 st = {acc[2 * cc], acc[2 * cc + 1]};
    __builtin_nontemporal_store(st, (f32x2*)&out_rec[(size_t)b * ND + cc * 128 + lane * 2]);
  }

  // ---- fused sparse-row writes: 4 rows sequential, LDS presence bitmap
  __syncthreads();
  for (int r = 0; r < 4; ++r) {
    bm[tid] = 0u;
    __syncthreads();
    if (tid < k) {
      int ix = seli_s[r][tid];
      atomicOr(&bm[ix >> 5], 1u << (ix & 31));
    }
    __syncthreads();
    float* rowp = out_sc + (size_t)(blockIdx.x * 4 + r) * NF;
#pragma unroll
    for (int i = 0; i < 8; ++i) {
      int o = (tid + (i << 8)) << 2;  // float offset, multiple of 4
      unsigned nib = (bm[o >> 5] >> (o & 31)) & 0xFu;
      f32x4 val = {0.f, 0.f, 0.f, 0.f};
      if (nib) {
#pragma unroll
        for (int j = 0; j < 4; ++j) {
          if ((nib >> j) & 1) {
            int idx = o + j;
            float bestv = 0.f;
            for (int t2 = 0; t2 < k; ++t2)
              if (seli_s[r][t2] == idx && selv_s[r][t2] > bestv) bestv = selv_s[r][t2];
            val[j] = bestv;
          }
        }
      }
      __builtin_nontemporal_store(val, (f32x4*)&rowp[o]);
    }
    __syncthreads();
  }
}

// ---------------------------------------------------------------------------
extern "C" void kernel_launch(void* const* d_in, const int* in_sizes, int n_in,
                              void* d_out, int out_size, void* d_ws, size_t ws_size,
                              hipStream_t stream) {
  const float* x        = (const float*)d_in[0];
  const float* W_enc    = (const float*)d_in[1];
  const float* b_enc    = (const float*)d_in[2];
  const float* W_dec    = (const float*)d_in[3];
  const float* dec_bias = (const float*)d_in[4];
  const int*   kptr     = (const int*)d_in[5];

  float* out_rec = (float*)d_out;                    // [NB, ND] (glist overlay)
  float* out_sc  = (float*)d_out + (size_t)NB * ND;  // [NB, NF]

  // glist overlays out_rec row-for-row: GSEG*4 B == ND*4 B == 3072 B per row
  unsigned* glist = (unsigned*)out_rec;              // 48 MB, rewritten by GEMM

  // Xbf/Wbf carved from the sparse-code output region (dead after GEMM;
  // overwritten by ksel's fused sparse writes afterwards)
  char* scb = (char*)out_sc;
  unsigned short* Xbf = (unsigned short*)scb;                 // 24 MB
  unsigned short* Wbf = (unsigned short*)(scb + 25165824);    // 12 MB

  char* ws = (char*)d_ws;
  unsigned short* WdecBf = (unsigned short*)ws;        // 12,582,912 B
  float* beta = (float*)(ws + 12582912);               //     32,768 B

  cvt_bf16_k<<<(NB * ND) / 2048, 256, 0, stream>>>(x, Xbf);
  cvtW_beta_k<<<NF / 4, 256, 0, stream>>>(W_enc, b_enc, dec_bias, Wbf, beta);
  transpose_bf_k<<<dim3(NF / 32, ND / 32), 256, 0, stream>>>(W_dec, WdecBf);
  enc_gemm_bf16<<<dim3(NF / 128, NB / 128), 256, 0, stream>>>(Xbf, Wbf, beta, glist);
  ksel_k<<<NB / 4, 256, 0, stream>>>(glist, x, W_enc, beta, WdecBf, dec_bias, kptr,
                                     out_rec, out_sc);
}

// Round 19
// 529.264 us; speedup vs baseline: 14.7230x; 1.2658x over previous
//
#include <hip/hip_runtime.h>

#define NB 16384
#define ND 768
#define NF 8192
#define CMAX 512        // ksel compact list cap per row
#define SEGW 16         // glist slots per (row,tile) segment
#define GSEG 1024       // glist u32 per row (64 tiles x 16 slots)
#define AMAX 128        // ambiguous cap per row (expect ~13)
#define MARG 0.07f      // classification margin (>= 2x bf16-GEMM act error bound)
#define THETA0 2.0f     // GEMM-side candidate threshold (bf16-exact)
#define THETA0_BITS 0x4000u

typedef __attribute__((ext_vector_type(8))) short bf16x8;
typedef __attribute__((ext_vector_type(4))) float f32x4;
typedef __attribute__((ext_vector_type(4))) unsigned int u32x4;
typedef __attribute__((ext_vector_type(2))) float f32x2;

__device__ inline unsigned short f2bf(float f) {
  unsigned u = __float_as_uint(f);
  unsigned r = (u + 0x7FFFu + ((u >> 16) & 1u)) >> 16;
  return (unsigned short)r;
}
__device__ inline float bfbits2f(unsigned u16) { return __uint_as_float(u16 << 16); }

// ---------------------------------------------------------------------------
// prep_k: fused {x->bf16 | W_enc->bf16 + beta | W_dec transpose->bf16}
// dispatch on blockIdx.x: [0,6144) cvt-x, [6144,8192) cvtW+beta, [8192,14336) T.
__global__ __launch_bounds__(256) void prep_k(
    const float* __restrict__ x, const float* __restrict__ W_enc,
    const float* __restrict__ b_enc, const float* __restrict__ W_dec,
    const float* __restrict__ dec_bias,
    unsigned short* __restrict__ Xbf, unsigned short* __restrict__ Wbf,
    float* __restrict__ beta, unsigned short* __restrict__ WdecBf) {
  __shared__ float smem[32 * 33];
  const int tid = threadIdx.x;
  const int bidx = blockIdx.x;

  if (bidx < 6144) {
    // ---- x -> bf16, 8 floats/thread
    size_t t = (size_t)bidx * 256 + tid;
    const float4* i4 = (const float4*)x;
    float4 a = i4[t * 2], b = i4[t * 2 + 1];
    ((ushort4*)Xbf)[t * 2]     = make_ushort4(f2bf(a.x), f2bf(a.y), f2bf(a.z), f2bf(a.w));
    ((ushort4*)Xbf)[t * 2 + 1] = make_ushort4(f2bf(b.x), f2bf(b.y), f2bf(b.z), f2bf(b.w));
  } else if (bidx < 8192) {
    // ---- W_enc -> bf16 + beta[f] = b_enc[f] - dot(dec_bias, W_enc[f])
    float* db = smem;
    const int wave = tid >> 6, lane = tid & 63;
    db[tid] = dec_bias[tid];
    db[tid + 256] = dec_bias[tid + 256];
    db[tid + 512] = dec_bias[tid + 512];
    __syncthreads();
    const int f = (bidx - 6144) * 4 + wave;
    const float* wr = W_enc + (size_t)f * ND + lane * 12;
    float4 v0 = *(const float4*)(wr);
    float4 v1 = *(const float4*)(wr + 4);
    float4 v2 = *(const float4*)(wr + 8);
    const float* d = &db[lane * 12];
    float s = 0.f;
    s = fmaf(v0.x, d[0], s);  s = fmaf(v0.y, d[1], s);
    s = fmaf(v0.z, d[2], s);  s = fmaf(v0.w, d[3], s);
    s = fmaf(v1.x, d[4], s);  s = fmaf(v1.y, d[5], s);
    s = fmaf(v1.z, d[6], s);  s = fmaf(v1.w, d[7], s);
    s = fmaf(v2.x, d[8], s);  s = fmaf(v2.y, d[9], s);
    s = fmaf(v2.z, d[10], s); s = fmaf(v2.w, d[11], s);
    unsigned short* ow = Wbf + (size_t)f * ND + lane * 12;
    *(ushort4*)(ow)     = make_ushort4(f2bf(v0.x), f2bf(v0.y), f2bf(v0.z), f2bf(v0.w));
    *(ushort4*)(ow + 4) = make_ushort4(f2bf(v1.x), f2bf(v1.y), f2bf(v1.z), f2bf(v1.w));
    *(ushort4*)(ow + 8) = make_ushort4(f2bf(v2.x), f2bf(v2.y), f2bf(v2.z), f2bf(v2.w));
#pragma unroll
    for (int off = 32; off; off >>= 1) s += __shfl_down(s, off);
    if (lane == 0) beta[f] = b_enc[f] - s;
  } else {
    // ---- W_dec [ND][NF] fp32 -> WdecBf [NF][ND] bf16 (32x32 tiles)
    float (*tile)[33] = (float (*)[33])smem;
    const int lin = bidx - 8192;
    const int bx = lin & 255;   // f-tile (NF/32 = 256)
    const int by = lin >> 8;    // d-tile (ND/32 = 24)
    int lx = tid & 31;
    int ty = tid >> 5;
    int xg = bx * 32 + lx;  // f
    for (int j = ty; j < 32; j += 8) {
      int y = by * 32 + j;  // d
      tile[j][lx] = W_dec[(size_t)y * NF + xg];
    }
    __syncthreads();
    int xo = by * 32 + lx;  // d
    for (int j = ty; j < 32; j += 8) {
      int yo = bx * 32 + j;  // f
      WdecBf[(size_t)yo * ND + xo] = f2bf(tile[lx][j]);
    }
  }
}

// ---------------------------------------------------------------------------
// bf16 MFMA GEMM v8.1 (round-16 proven): single-buffered BK=64, 32 KB LDS,
// 5 blocks/CU pin, hoisted frag offsets, fused 16-slot candidate segments.
__global__ __launch_bounds__(256, 5) void enc_gemm_bf16(
    const unsigned short* __restrict__ Xb, const unsigned short* __restrict__ Wb,
    const float* __restrict__ beta, unsigned* __restrict__ glist) {
  __shared__ __align__(1024) unsigned short As[128 * 64];  // 16 KB
  __shared__ __align__(1024) unsigned short Bs[128 * 64];  // 16 KB
  const int tid = threadIdx.x;
  const int wave = tid >> 6, lane = tid & 63;
  const int wm = wave >> 1, wn = wave & 1;

  const int orig = blockIdx.y * gridDim.x + blockIdx.x;  // 0..8191
  const int xcd = orig & 7;
  const int local = orig >> 3;
  const int tcol = local >> 4;          // 0..63
  const int trow = (xcd << 4) + (local & 15);
  const int brow = trow << 7;
  const int bcol = tcol << 7;

  f32x4 acc[4][4] = {};

  const int srow = tid >> 3;                                   // 0..31
  const int scol = (((tid & 7) ^ ((tid >> 3) & 7)) << 3);      // pre-swizzled source chunk
  const unsigned short* gA = Xb + (size_t)(brow + srow) * ND + scol;
  const unsigned short* gB = Wb + (size_t)(bcol + srow) * ND + scol;

  int aoff[2][4], boff[2][4];
#pragma unroll
  for (int kk2 = 0; kk2 < 2; ++kk2) {
    const int chunk = ((kk2 << 5) + ((lane >> 4) << 3)) >> 3;
    const int sw = chunk ^ (lane & 7);
#pragma unroll
    for (int m = 0; m < 4; ++m)
      aoff[kk2][m] = ((wm << 6) + (lane & 15) + (m << 4)) * 64 + (sw << 3);
#pragma unroll
    for (int n = 0; n < 4; ++n)
      boff[kk2][n] = ((wn << 6) + (lane & 15) + (n << 4)) * 64 + (sw << 3);
  }

#pragma unroll 1
  for (int step = 0; step < 12; ++step) {
    const int kt = step * 64;
#pragma unroll
    for (int i = 0; i < 4; ++i) {
      __builtin_amdgcn_global_load_lds(
          (const __attribute__((address_space(1))) void*)(gA + (size_t)(i * 32) * ND + kt),
          (__attribute__((address_space(3))) void*)(As + (i * 32 + wave * 8) * 64), 16, 0, 0);
      __builtin_amdgcn_global_load_lds(
          (const __attribute__((address_space(1))) void*)(gB + (size_t)(i * 32) * ND + kt),
          (__attribute__((address_space(3))) void*)(Bs + (i * 32 + wave * 8) * 64), 16, 0, 0);
    }
    __syncthreads();
#pragma unroll
    for (int kk2 = 0; kk2 < 2; ++kk2) {
      bf16x8 a[4], bvv[4];
#pragma unroll
      for (int m = 0; m < 4; ++m) a[m] = *(const bf16x8*)&As[aoff[kk2][m]];
#pragma unroll
      for (int n = 0; n < 4; ++n) bvv[n] = *(const bf16x8*)&Bs[boff[kk2][n]];
#pragma unroll
      for (int m = 0; m < 4; ++m)
#pragma unroll
        for (int n = 0; n < 4; ++n)
          acc[m][n] = __builtin_amdgcn_mfma_f32_16x16x32_bf16(a[m], bvv[n], acc[m][n], 0, 0, 0);
    }
    __syncthreads();
  }

  // ---- epilogue: candidate segments overlaid on the (now dead) As buffer
  unsigned (*wseg)[SEGW] = (unsigned (*)[SEGW])As;        // 128 x 16 u32 = 8 KB
  unsigned* wcnt = (unsigned*)(As + 4096);                // 512 B (byte off 8 KB)
#pragma unroll
  for (int i = 0; i < 8; ++i) ((unsigned*)wseg)[tid + 256 * i] = 0u;
  if (tid < 128) wcnt[tid] = 0u;
  __syncthreads();

#pragma unroll
  for (int n = 0; n < 4; ++n) {
    float bet = beta[bcol + (wn << 6) + (n << 4) + (lane & 15)];
#pragma unroll
    for (int m = 0; m < 4; ++m) {
#pragma unroll
      for (int r = 0; r < 4; ++r) {
        int row_l = (wm << 6) + (m << 4) + ((lane >> 4) << 2) + r;
        int col_l = (wn << 6) + (n << 4) + (lane & 15);
        float v = fmaxf(acc[m][n][r] + bet, 0.f);
        unsigned short ub = f2bf(v);
        if (ub >= (unsigned short)THETA0_BITS) {
          unsigned p = atomicAdd(&wcnt[row_l], 1u);
          if (p < SEGW) wseg[row_l][p] = ((unsigned)ub << 16) | (unsigned)(bcol + col_l);
        }
      }
    }
  }
  __syncthreads();
  {
    int row = tid >> 1;
    int sbase = (tid & 1) << 3;
    u32x4 v0 = *(const u32x4*)&wseg[row][sbase];
    u32x4 v1 = *(const u32x4*)&wseg[row][sbase + 4];
    if (sbase == 0 && wcnt[row] > SEGW) v0[0] = 0xFFFFFFFFu;  // overflow sentinel
    unsigned* dst = &glist[(size_t)(brow + row) * GSEG + (tcol << 4)];
    __builtin_nontemporal_store(v0, (u32x4*)&dst[sbase]);
    __builtin_nontemporal_store(v1, (u32x4*)&dst[sbase + 4]);
  }
}

// ---------------------------------------------------------------------------
// ksel v7 (round-16 proven): wave-per-row fast path on GEMM-built segments;
// invalid -> block-cooperative exact fp32 recompute (deterministic).
__global__ __launch_bounds__(256, 6) void ksel_k(
    const unsigned* __restrict__ glist,
    const float* __restrict__ x, const float* __restrict__ W_enc,
    const float* __restrict__ beta, const unsigned short* __restrict__ WdecBf,
    const float* __restrict__ dec_bias, const int* __restrict__ kptr,
    float* __restrict__ out_rec, float* __restrict__ g_vals, int* __restrict__ g_idxs) {
  const int tid = threadIdx.x, wave = tid >> 6, lane = tid & 63;
  const int b = blockIdx.x * 4 + wave;
  int k = *kptr; k = k < 1 ? 1 : (k > 64 ? 64 : k);
  const unsigned kk = (unsigned)k;

  __shared__ unsigned clist_s[4][CMAX];
  __shared__ unsigned long long aval_s[4][AMAX];
  __shared__ float selv_s[4][64];
  __shared__ int seli_s[4][64];
  __shared__ int ctrC_s[4], ctrW_s[4], ctrA_s[4];
  __shared__ int blkFb;
  __shared__ float fb_x[ND];
  __shared__ unsigned long long fbl[512];
  __shared__ unsigned fb_thrmax[256];
  __shared__ unsigned long long fb_red[4];
  __shared__ unsigned fb_cnt4[4];
  __shared__ unsigned fbcnt;

  unsigned* clist = clist_s[wave];
  unsigned long long* aval = aval_s[wave];
  float* selv = selv_s[wave];
  int* seli = seli_s[wave];

  if (tid == 0) blkFb = 0;
  if (lane == 0) { ctrC_s[wave] = 0; ctrW_s[wave] = 0; ctrA_s[wave] = 0; }

  bool bad = false;
  {
    const u32x4* seg4 = (const u32x4*)(glist + (size_t)b * GSEG);
#pragma unroll
    for (int ii = 0; ii < 4; ++ii) {
      u32x4 e4 = __builtin_nontemporal_load(&seg4[lane + (ii << 6)]);
#pragma unroll
      for (int q = 0; q < 4; ++q) {
        unsigned e = e4[q];
        if (e) {
          if ((e & 0xFFFFu) >= (unsigned)NF) bad = true;  // sentinel
          else {
            int p = atomicAdd(&ctrC_s[wave], 1);
            if (p < CMAX) clist[p] = e;
          }
        }
      }
    }
  }
  bad = (__ballot(bad) != 0ull);
  int n = ctrC_s[wave]; if (n > CMAX) n = CMAX;

  unsigned ks[8];
#pragma unroll
  for (int ii = 0; ii < 8; ++ii) {
    int j = lane + (ii << 6);
    ks[ii] = (j < n) ? (clist[j] >> 16) : 0u;
  }
  unsigned T = 0;
  for (int bit = 14; bit >= 0; --bit) {
    unsigned probe = T | (1u << bit);
    int c = 0;
#pragma unroll
    for (int ii = 0; ii < 8; ++ii) c += (ks[ii] >= probe);
#pragma unroll
    for (int off = 32; off; off >>= 1) c += __shfl_xor(c, off);
    if (c >= (int)kk) T = probe;
  }
  float tauf = bfbits2f(T);

  bool valid = !bad && (n >= k) && (tauf >= THETA0 + MARG);
  if (lane == 0 && !valid) atomicOr(&blkFb, 1);
  __syncthreads();

  if (!blkFb) {
    const float thrW = tauf + MARG;
    const float thrA = tauf - MARG;
    for (int j = lane; j < n; j += 64) {
      unsigned e = clist[j];
      float v = bfbits2f(e >> 16);
      int idx = (int)(e & 0xFFFFu);
      if (v > thrW) {
        int p = atomicAdd(&ctrW_s[wave], 1);
        if (p < 63) { selv[p] = v; seli[p] = idx; }
      } else if (v >= thrA) {
        int p = atomicAdd(&ctrA_s[wave], 1);
        if (p < AMAX) aval[p] = (unsigned long long)(unsigned)idx;
      }
    }
    __syncthreads();
    int c = ctrW_s[wave]; if (c > 63) c = 63; if (c > k - 1) c = k - 1;
    int na = ctrA_s[wave]; if (na > AMAX) na = AMAX;

    float xr[12];
#pragma unroll
    for (int cc = 0; cc < 12; ++cc)
      xr[cc] = __builtin_nontemporal_load(&x[(size_t)b * ND + lane + 64 * cc]);
    for (int j = 0; j < na; j += 2) {
      int f0 = (int)(unsigned)aval[j];
      int f1 = (j + 1 < na) ? (int)(unsigned)aval[j + 1] : f0;
      const float* w0 = W_enc + (size_t)f0 * ND;
      const float* w1 = W_enc + (size_t)f1 * ND;
      float s0 = 0.f, s1 = 0.f;
#pragma unroll
      for (int cc = 0; cc < 12; ++cc) {
        s0 = fmaf(xr[cc], w0[lane + 64 * cc], s0);
        s1 = fmaf(xr[cc], w1[lane + 64 * cc], s1);
      }
#pragma unroll
      for (int off = 32; off; off >>= 1) {
        s0 += __shfl_xor(s0, off);
        s1 += __shfl_xor(s1, off);
      }
      if (lane == 0) {
        float v0 = fmaxf(s0 + beta[f0], 0.f);
        aval[j] = (((unsigned long long)__float_as_uint(v0)) << 13) | (unsigned)(8191 - f0);
        if (j + 1 < na) {
          float v1 = fmaxf(s1 + beta[f1], 0.f);
          aval[j + 1] = (((unsigned long long)__float_as_uint(v1)) << 13) | (unsigned)(8191 - f1);
        }
      }
    }
    __syncthreads();

    unsigned long long p0 = (lane < na) ? aval[lane] : 0ull;
    unsigned long long p1 = (lane + 64 < na) ? aval[lane + 64] : 0ull;
    int rounds = k - c; if (rounds < 0) rounds = 0;
    for (int r = 0; r < rounds; ++r) {
      unsigned long long m = p0 > p1 ? p0 : p1;
#pragma unroll
      for (int off = 32; off; off >>= 1) {
        unsigned long long o = __shfl_xor(m, off);
        if (o > m) m = o;
      }
      if (lane == 0) {
        if (m) { selv[c + r] = __uint_as_float((unsigned)(m >> 13)); seli[c + r] = 8191 - (int)(m & 0x1FFFull); }
        else   { selv[c + r] = 0.f; seli[c + r] = 0; }
      }
      if (p0 == m) p0 = 0;
      if (p1 == m) p1 = 0;
    }
    __syncthreads();
  } else {
    for (int r = 0; r < 4; ++r) {
      const int row = blockIdx.x * 4 + r;
      fb_x[tid] = x[(size_t)row * ND + tid];
      fb_x[tid + 256] = x[(size_t)row * ND + tid + 256];
      fb_x[tid + 512] = x[(size_t)row * ND + tid + 512];
      __syncthreads();
      unsigned mymax = 0u;
      for (int j = 0; j < 32; ++j) {
        int f = tid * 32 + j;
        const float* w = W_enc + (size_t)f * ND;
        float s = 0.f;
#pragma unroll 8
        for (int d = 0; d < ND; ++d) s = fmaf(fb_x[d], w[d], s);
        unsigned bits = __float_as_uint(fmaxf(s + beta[f], 0.f));
        if (bits > mymax) mymax = bits;
      }
      fb_thrmax[tid] = mymax;
      __syncthreads();
      unsigned L = 0;
      for (int bit = 30; bit >= 0; --bit) {
        unsigned probe = L | (1u << bit);
        unsigned long long bl = __ballot(fb_thrmax[tid] >= probe);
        if (lane == 0) fb_cnt4[wave] = (unsigned)__popcll(bl);
        __syncthreads();
        unsigned tot = fb_cnt4[0] + fb_cnt4[1] + fb_cnt4[2] + fb_cnt4[3];
        if (tot >= kk) L = probe;
        __syncthreads();
      }
      if (tid == 0) fbcnt = 0u;
      __syncthreads();
      for (int j = 0; j < 32; ++j) {
        int f = tid * 32 + j;
        const float* w = W_enc + (size_t)f * ND;
        float s = 0.f;
#pragma unroll 8
        for (int d = 0; d < ND; ++d) s = fmaf(fb_x[d], w[d], s);
        unsigned bits = __float_as_uint(fmaxf(s + beta[f], 0.f));
        if (bits >= L) {
          unsigned p = atomicAdd(&fbcnt, 1u);
          if (p < 512) fbl[p] = (((unsigned long long)bits) << 13) | (unsigned)(8191 - f);
        }
      }
      __syncthreads();
      int n2 = (int)(fbcnt < 512u ? fbcnt : 512u);
      for (int rr = 0; rr < k; ++rr) {
        unsigned long long best = 0ull;
        for (int j2 = tid; j2 < n2; j2 += 256)
          if (fbl[j2] > best) best = fbl[j2];
#pragma unroll
        for (int off = 32; off; off >>= 1) {
          unsigned long long o = __shfl_xor(best, off);
          if (o > best) best = o;
        }
        if (lane == 0) fb_red[wave] = best;
        __syncthreads();
        unsigned long long m = fb_red[0];
#pragma unroll
        for (int w2 = 1; w2 < 4; ++w2)
          if (fb_red[w2] > m) m = fb_red[w2];
        if (tid == 0) {
          if (m) { selv_s[r][rr] = __uint_as_float((unsigned)(m >> 13)); seli_s[r][rr] = 8191 - (int)(m & 0x1FFFull); }
          else   { selv_s[r][rr] = 0.f; seli_s[r][rr] = 0; }
        }
        for (int j2 = tid; j2 < n2; j2 += 256)
          if (fbl[j2] == m) fbl[j2] = 0ull;
        __syncthreads();
      }
      __syncthreads();
    }
  }

  if (lane < k) {
    g_vals[(size_t)b * 64 + lane] = selv[lane];
    g_idxs[(size_t)b * 64 + lane] = seli[lane];
  }

  float acc[12];
#pragma unroll
  for (int cc = 0; cc < 6; ++cc) {
    float2 db = *(const float2*)&dec_bias[cc * 128 + lane * 2];
    acc[2 * cc] = db.x; acc[2 * cc + 1] = db.y;
  }
#define RECON_TERM(r)                                                          \
  {                                                                            \
    int f = seli[r]; float v = selv[r];                                        \
    const unsigned short* wd = WdecBf + (size_t)f * ND;                        \
    _Pragma("unroll")                                                          \
    for (int cc = 0; cc < 6; ++cc) {                                           \
      unsigned pr = *(const unsigned*)&wd[cc * 128 + lane * 2];                \
      acc[2 * cc] = fmaf(v, bfbits2f(pr & 0xFFFFu), acc[2 * cc]);              \
      acc[2 * cc + 1] = fmaf(v, bfbits2f(pr >> 16), acc[2 * cc + 1]);          \
    }                                                                          \
  }
  if (k == 32) {
#pragma unroll
    for (int r = 0; r < 32; ++r) RECON_TERM(r)
  } else {
    for (int r = 0; r < k; ++r) RECON_TERM(r)
  }
#pragma unroll
  for (int cc = 0; cc < 6; ++cc) {
    f32x2 st = {acc[2 * cc], acc[2 * cc + 1]};
    __builtin_nontemporal_store(st, (f32x2*)&out_rec[(size_t)b * ND + cc * 128 + lane * 2]);
  }
}

// ---------------------------------------------------------------------------
__global__ __launch_bounds__(256) void d2_sparse_k(
    const float* __restrict__ g_vals, const int* __restrict__ g_idxs,
    const int* __restrict__ kptr, float* __restrict__ out_sc) {
  const int b = blockIdx.x, tid = threadIdx.x;
  int k = *kptr; k = k < 1 ? 1 : (k > 64 ? 64 : k);
  __shared__ float row[NF];
  __shared__ float sv[64];
  __shared__ int si[64];
  if (tid < k) { sv[tid] = g_vals[(size_t)b * 64 + tid]; si[tid] = g_idxs[(size_t)b * 64 + tid]; }
  float4* r4 = (float4*)row;
#pragma unroll
  for (int i = 0; i < 8; ++i) r4[tid + 256 * i] = make_float4(0.f, 0.f, 0.f, 0.f);
  __syncthreads();
  if (tid < k) row[si[tid]] = sv[tid];
  __syncthreads();
  f32x4* o4 = (f32x4*)(out_sc + (size_t)b * NF);
  const f32x4* r4v = (const f32x4*)row;
#pragma unroll
  for (int i = 0; i < 8; ++i)
    __builtin_nontemporal_store(r4v[tid + 256 * i], &o4[tid + 256 * i]);
}

// ---------------------------------------------------------------------------
extern "C" void kernel_launch(void* const* d_in, const int* in_sizes, int n_in,
                              void* d_out, int out_size, void* d_ws, size_t ws_size,
                              hipStream_t stream) {
  const float* x        = (const float*)d_in[0];
  const float* W_enc    = (const float*)d_in[1];
  const float* b_enc    = (const float*)d_in[2];
  const float* W_dec    = (const float*)d_in[3];
  const float* dec_bias = (const float*)d_in[4];
  const int*   kptr     = (const int*)d_in[5];

  float* out_rec = (float*)d_out;
  float* out_sc  = (float*)d_out + (size_t)NB * ND;

  // scratch carved from the sparse-code output region (rewritten by d2 last)
  char* scb = (char*)out_sc;
  unsigned*       glist = (unsigned*)scb;                      // 64 MB
  unsigned short* Xbf   = (unsigned short*)(scb + 67108864);   // 24 MB
  unsigned short* Wbf   = (unsigned short*)(scb + 92274688);   // 12 MB

  char* ws = (char*)d_ws;
  unsigned short* WdecBf = (unsigned short*)ws;        // 12,582,912 B
  float* beta   = (float*)(ws + 12582912);             //     32,768 B
  float* g_vals = (float*)(ws + 12615680);             //  4,194,304 B
  int*   g_idxs = (int*)(ws + 16809984);               //  4,194,304 B

  prep_k<<<14336, 256, 0, stream>>>(x, W_enc, b_enc, W_dec, dec_bias,
                                    Xbf, Wbf, beta, WdecBf);
  enc_gemm_bf16<<<dim3(NF / 128, NB / 128), 256, 0, stream>>>(Xbf, Wbf, beta, glist);
  ksel_k<<<NB / 4, 256, 0, stream>>>(glist, x, W_enc, beta, WdecBf, dec_bias, kptr,
                                     out_rec, g_vals, g_idxs);
  d2_sparse_k<<<NB, 256, 0, stream>>>(g_vals, g_idxs, kptr, out_sc);
}